// Round 10
// baseline (204.051 us; speedup 1.0000x reference)
//
#include <hip/hip_runtime.h>
#include <stdint.h>

// GlobalAddAttention: B=64 graphs, L=256 (1 metal + 255 nodes), E=512, H=8, Dh=64
// Pipeline: pack(bf16) -> QKV GEMM (MFMA) -> attention (MFMA, full-S) -> out GEMM (MFMA)

#define EMB    512
#define NH     8
#define NGR    64
#define SEQL   256
#define DHEAD  64
#define MROWS  16384   // NGR*SEQL

typedef __attribute__((ext_vector_type(4))) float f32x4;
typedef __attribute__((ext_vector_type(4))) short s16x4;
typedef __attribute__((ext_vector_type(8))) short s16x8;

__device__ __forceinline__ short f2bf(float f) {
  uint32_t u = __builtin_bit_cast(uint32_t, f);
  u += 0x7FFFu + ((u >> 16) & 1u);           // round-to-nearest-even
  return (short)(u >> 16);
}

__device__ __forceinline__ f32x4 mfma16(s16x8 a, s16x8 b, f32x4 c) {
  return __builtin_amdgcn_mfma_f32_16x16x32_bf16(a, b, c, 0, 0, 0);
}

__device__ __forceinline__ void gload_lds16(const void* g, void* l) {
  __builtin_amdgcn_global_load_lds(
      (const __attribute__((address_space(1))) void*)g,
      (__attribute__((address_space(3))) void*)l, 16, 0, 0);
}

// ---------------------------------------------------------------- pack kernels

// value[b*256+l][e] = (l==0) ? metal_x[b][e] : x[b*255+l-1][e], as bf16
__global__ void pack_value(const float* __restrict__ x, const float* __restrict__ mx,
                           short* __restrict__ val) {
  int gid = blockIdx.x * 256 + threadIdx.x;       // 2,097,152 threads, 4 elems each
  int i = gid << 2;
  int row = i >> 9, col = i & 511;
  int b = row >> 8, l = row & 255;
  const float* src = l ? x  + ((size_t)(b * 255 + l - 1) << 9) + col
                       : mx + ((size_t)b << 9) + col;
  f32x4 f = *(const f32x4*)src;
  s16x4 o = { f2bf(f[0]), f2bf(f[1]), f2bf(f[2]), f2bf(f[3]) };
  *(s16x4*)(val + i) = o;
}

// wqkv[(which*512+o)*512+k] bf16 (which: 0=q,1=k,2=v); wo bf16; bias_qkv fp32 concat
__global__ void pack_w(const float* __restrict__ Wq, const float* __restrict__ Wk,
                       const float* __restrict__ Wv, const float* __restrict__ Wo,
                       const float* __restrict__ bq, const float* __restrict__ bk,
                       const float* __restrict__ bv,
                       short* __restrict__ wqkv, short* __restrict__ wo,
                       float* __restrict__ bias_qkv) {
  int gid = blockIdx.x * 256 + threadIdx.x;       // 262,144 threads
  int i = gid << 2;
  const float* src; short* dst;
  if (i < 786432) {
    int which = i >> 18, off = i & 262143;
    src = (which == 0 ? Wq : which == 1 ? Wk : Wv) + off;
    dst = wqkv + i;
  } else {
    int off = i - 786432;
    src = Wo + off; dst = wo + off;
  }
  f32x4 f = *(const f32x4*)src;
  s16x4 o = { f2bf(f[0]), f2bf(f[1]), f2bf(f[2]), f2bf(f[3]) };
  *(s16x4*)dst = o;
  if (gid < 1536)
    bias_qkv[gid] = gid < 512 ? bq[gid] : gid < 1024 ? bk[gid - 512] : bv[gid - 1024];
}

// ------------------------------------------------------------------- GEMM
// C[M=16384, N] = A[M,512](bf16) @ Bt[N,512]^T + bias.
// 128x128 tile, BK=32, 4 waves (2x2), 4x4 16x16x32 frags per wave.
// Minimum-2-phase pipeline (T3 recipe, m230-V0): double-buffered LDS,
// prefetch STAGE(t+1) issued BEFORE compute(t), ONE __syncthreads per iter.
// mode 0: scatter q/k/v [B,H,L,64] bf16.  mode 1: scatter final fp32 output.
#define BM 128
#define BN 128
#define BK 32

__global__ __launch_bounds__(256, 2) void gemm_bt(
    const short* __restrict__ A, const short* __restrict__ Bt,
    const float* __restrict__ bias, int mode,
    short* __restrict__ qb, short* __restrict__ kb, short* __restrict__ vb,
    float* __restrict__ outp) {
  __shared__ short As[2][BM * BK];
  __shared__ short Bs[2][BN * BK];
  const int tid = threadIdx.x;
  const int lane = tid & 63, wid = tid >> 6;
  const int wr = wid >> 1, wc = wid & 1;
  const int l15 = lane & 15, l4 = lane >> 4;
  const int bm = blockIdx.x * BM, bn = blockIdx.y * BN;

  f32x4 acc[4][4];
#pragma unroll
  for (int r = 0; r < 4; ++r)
#pragma unroll
    for (int c = 0; c < 4; ++c) acc[r][c] = (f32x4){0.f, 0.f, 0.f, 0.f};

  // prologue: stage K-tile 0 into buffer 0
#pragma unroll
  for (int i = 0; i < 2; ++i) {
    int idx = i * 256 + tid;
    int row = idx >> 2, cc = (idx & 3) * 8;
    gload_lds16(A + (size_t)(bm + row) * 512 + cc, &As[0][idx * 8]);
    gload_lds16(Bt + (size_t)(bn + row) * 512 + cc, &Bs[0][idx * 8]);
  }
  __syncthreads();                     // drain prologue staging

  int cur = 0;
  for (int t = 0; t < 512 / BK; ++t) {
    // issue next-tile prefetch FIRST (flies under this tile's compute)
    if (t < 512 / BK - 1) {
      const int bk = (t + 1) * BK;
#pragma unroll
      for (int i = 0; i < 2; ++i) {
        int idx = i * 256 + tid;
        int row = idx >> 2, cc = (idx & 3) * 8;
        gload_lds16(A + (size_t)(bm + row) * 512 + bk + cc, &As[cur ^ 1][idx * 8]);
        gload_lds16(Bt + (size_t)(bn + row) * 512 + bk + cc, &Bs[cur ^ 1][idx * 8]);
      }
    }

    s16x8 af[4], bf[4];
#pragma unroll
    for (int r = 0; r < 4; ++r)
      af[r] = *(const s16x8*)(&As[cur][(wr * 64 + r * 16 + l15) * BK + l4 * 8]);
#pragma unroll
    for (int c = 0; c < 4; ++c)
      bf[c] = *(const s16x8*)(&Bs[cur][(wc * 64 + c * 16 + l15) * BK + l4 * 8]);
#pragma unroll
    for (int r = 0; r < 4; ++r)
#pragma unroll
      for (int c = 0; c < 4; ++c)
        acc[r][c] = mfma16(af[r], bf[c], acc[r][c]);

    __syncthreads();                   // vmcnt(0)+lgkmcnt(0)+barrier: prefetch
    cur ^= 1;                          // landed, all reads of buf[cur] retired
  }

  // epilogue: D layout col = lane&15, row = (lane>>4)*4 + reg  [m89-verified]
#pragma unroll
  for (int r = 0; r < 4; ++r) {
    int row0 = bm + wr * 64 + r * 16 + l4 * 4;
#pragma unroll
    for (int c = 0; c < 4; ++c) {
      int col_g = bn + wc * 64 + c * 16 + l15;
      float bvv = bias[col_g];
#pragma unroll
      for (int j = 0; j < 4; ++j) {
        float v = acc[r][c][j] + bvv;
        int row = row0 + j;
        int b = row >> 8, lrow = row & 255;
        if (mode == 0) {
          int which = col_g >> 9, rem = col_g & 511;
          int h = rem >> 6, dh = rem & 63;
          size_t idx = ((size_t)((b * 8 + h) * 256 + lrow)) * 64 + dh;
          (which == 0 ? qb : which == 1 ? kb : vb)[idx] = f2bf(v);
        } else {
          // out_lb is [L,B,E]: l==0 -> metal block, else ((l-1)*64+b)*512+e
          size_t idx = (lrow == 0)
                         ? (size_t)16320 * 512 + (size_t)b * 512 + col_g
                         : ((size_t)(lrow - 1) * 64 + b) * 512 + col_g;
          outp[idx] = v;
        }
      }
    }
  }
}

// ---------------------------------------------------------------- attention
// grid = 2048 blocks: 4 blocks per (bh = b*8+h), each owning 64 query rows
// (4 waves x 16 rows). Was 2 blocks x (4 waves x 32 rows) — the full-S
// register footprint (128 VGPR/lane) capped occupancy at 2 waves/SIMD and
// left a 40K-cycle latency-bound critical path (R9: MfmaUtil 4.6%, VALUBusy
// 16%, HBM 11%). Halving per-wave S to s[16] (64 regs) + halving Pl lets
// 3 blocks/CU reside and halves the per-wave dependency chains.
// Block remap groups the 4 sibling blocks of one bh onto one XCD (L2 reuse
// of K/V): bh=(hb%8)*64+(hb/8)/4, quarter=(hb/8)%4 — bijective over 2048.
// NOTE: every loop touching s[] must be FULLY unrolled (rule #20).
#define VT_ROWB 544   // 272 bf16 per row (256 keys + pad), 16B aligned

__global__ __launch_bounds__(256, 2) void attn(
    const short* __restrict__ qb, const short* __restrict__ kb,
    const short* __restrict__ vb, short* __restrict__ attn_out) {
  __shared__ short VT[64 * 272];        // [d][key] swizzled, 34816 B
  __shared__ short Pl[4][16 * 72];      // per-wave P chunk (16 q-rows), 9216 B

  const int tid = threadIdx.x;
  const int lane = tid & 63, w = tid >> 6;
  const int l15 = lane & 15, l4 = lane >> 4;
  const int hb = blockIdx.x;
  const int bh = (hb & 7) * 64 + ((hb >> 3) >> 2);   // XCD-grouped (bijective)
  const int quarter = (hb >> 3) & 3;
  const size_t base = (size_t)bh * SEQL * DHEAD;

  // --- V -> VT[d][key] (bf16, XOR-swizzled so both write & b128 read are clean)
  {
    int d0 = (tid & 7) * 8;
    int krow = tid >> 3;                // 0..31
#pragma unroll
    for (int step = 0; step < 8; ++step) {
      int key = step * 32 + krow;
      s16x8 vv = *(const s16x8*)(vb + base + (size_t)key * 64 + d0);
#pragma unroll
      for (int j = 0; j < 8; ++j) {
        int d = d0 + j;
        int off = d * VT_ROWB + ((key * 2) ^ ((d << 1) & 0x70));
        *(short*)((char*)VT + off) = vv[j];
      }
    }
  }

  // --- Q A-frags (one 16-row tile x 2 k-slices)
  const int q0 = quarter * 64 + w * 16;
  s16x8 qf[2];
#pragma unroll
  for (int kk = 0; kk < 2; ++kk)
    qf[kk] = *(const s16x8*)(qb + base + (size_t)(q0 + l15) * 64 + kk * 32 + l4 * 8);

  __syncthreads();                      // VT ready for all waves

  // --- S = Q K^T  (per wave: 16 queries x 256 keys)
  f32x4 s[16];
#pragma unroll
  for (int ct = 0; ct < 16; ++ct) s[ct] = (f32x4){0.f, 0.f, 0.f, 0.f};

#pragma unroll                          // FULL unroll: ct must be compile-time
  for (int ct = 0; ct < 16; ++ct) {
    const short* kp = kb + base + (size_t)(ct * 16 + l15) * 64 + l4 * 8;
    s16x8 kf0 = *(const s16x8*)(kp);
    s16x8 kf1 = *(const s16x8*)(kp + 32);
    s[ct] = mfma16(qf[0], kf0, s[ct]);
    s[ct] = mfma16(qf[1], kf1, s[ct]);
  }

  // --- softmax (rows live in (lane>>4)*4+reg; reduce over 16 key-lanes)
  const float scale = 0.125f;           // 1/sqrt(64)
  float lsum[4];
#pragma unroll
  for (int j = 0; j < 4; ++j) {
    float m = -1e30f;
#pragma unroll
    for (int ct = 0; ct < 16; ++ct) m = fmaxf(m, s[ct][j]);
#pragma unroll
    for (int d = 1; d < 16; d <<= 1) m = fmaxf(m, __shfl_xor(m, d, 64));
    m *= scale;
    float ls = 0.f;
#pragma unroll
    for (int ct = 0; ct < 16; ++ct) {
      float p = __expf(s[ct][j] * scale - m);
      s[ct][j] = p;
      ls += p;
    }
#pragma unroll
    for (int d = 1; d < 16; d <<= 1) ls += __shfl_xor(ls, d, 64);
    lsum[j] = ls;
  }

  // --- O = P V  (chunked: stage P 64 keys at a time in per-wave LDS)
  f32x4 o[4];
#pragma unroll
  for (int jt = 0; jt < 4; ++jt) o[jt] = (f32x4){0.f, 0.f, 0.f, 0.f};

#pragma unroll                          // FULL unroll: ck must be compile-time
  for (int ck = 0; ck < 4; ++ck) {
#pragma unroll
    for (int c2 = 0; c2 < 4; ++c2)
#pragma unroll
      for (int j = 0; j < 4; ++j) {
        int q = l4 * 4 + j;             // 0..15
        int col = c2 * 16 + l15;
        Pl[w][q * 72 + col] = f2bf(s[ck * 4 + c2][j]);
      }
    // per-wave LDS: no barrier needed; compiler inserts lgkmcnt waits
#pragma unroll
    for (int kk = 0; kk < 2; ++kk) {
      s16x8 pf = *(const s16x8*)(&Pl[w][l15 * 72 + kk * 32 + l4 * 8]);
#pragma unroll
      for (int jt = 0; jt < 4; ++jt) {
        int d = jt * 16 + l15;
        int k0 = ck * 64 + kk * 32 + l4 * 8;
        int off = d * VT_ROWB + ((k0 * 2) ^ ((d << 1) & 0x70));
        s16x8 vf = *(const s16x8*)((const char*)VT + off);
        o[jt] = mfma16(pf, vf, o[jt]);
      }
    }
  }

  // --- normalize + store as bf16 A-matrix for the out-projection
  const int b = bh >> 3, h = bh & 7;
#pragma unroll
  for (int jt = 0; jt < 4; ++jt)
#pragma unroll
    for (int j = 0; j < 4; ++j) {
      float val = o[jt][j] / lsum[j];
      int qrow = q0 + l4 * 4 + j;
      int d = jt * 16 + l15;
      attn_out[(size_t)(b * 256 + qrow) * 512 + h * 64 + d] = f2bf(val);
    }
}

// ---------------------------------------------------------------- launch

extern "C" void kernel_launch(void* const* d_in, const int* in_sizes, int n_in,
                              void* d_out, int out_size, void* d_ws, size_t ws_size,
                              hipStream_t stream) {
  (void)in_sizes; (void)n_in; (void)out_size; (void)ws_size;
  const float* x  = (const float*)d_in[0];
  const float* mx = (const float*)d_in[1];
  // d_in[2] = batch indices (structure known statically; unused)
  const float* Wq = (const float*)d_in[3];
  const float* Wk = (const float*)d_in[4];
  const float* Wv = (const float*)d_in[5];
  const float* bq = (const float*)d_in[6];
  const float* bk = (const float*)d_in[7];
  const float* bv = (const float*)d_in[8];
  const float* Wo = (const float*)d_in[9];
  const float* bo = (const float*)d_in[10];
  float* out = (float*)d_out;

  char* ws = (char*)d_ws;
  short* value = (short*)(ws);                    // 16,777,216 B
  short* wqkv  = (short*)(ws + 16777216);         //  1,572,864 B
  short* wo    = (short*)(ws + 18350080);         //    524,288 B
  float* biasq = (float*)(ws + 18874368);         //      6,144 B
  short* qbuf  = (short*)(ws + 18880512);         // 16,777,216 B
  short* kbuf  = (short*)(ws + 35657728);         // 16,777,216 B
  short* vbuf  = (short*)(ws + 52434944);         // 16,777,216 B -> 69,212,160 total
  short* attn_o = value;                          // value dead after QKV GEMM

  pack_value<<<8192, 256, 0, stream>>>(x, mx, value);
  pack_w<<<1024, 256, 0, stream>>>(Wq, Wk, Wv, Wo, bq, bk, bv, wqkv, wo, biasq);
  gemm_bt<<<dim3(128, 12), 256, 0, stream>>>(value, wqkv, biasq, 0,
                                             qbuf, kbuf, vbuf, nullptr);
  attn<<<2048, 256, 0, stream>>>(qbuf, kbuf, vbuf, attn_o);
  gemm_bt<<<dim3(128, 4), 256, 0, stream>>>(attn_o, wo, bo, 1,
                                            nullptr, nullptr, nullptr, out);
}

// Round 11
// 187.581 us; speedup vs baseline: 1.0878x; 1.0878x over previous
//
#include <hip/hip_runtime.h>
#include <stdint.h>

// GlobalAddAttention: B=64 graphs, L=256 (1 metal + 255 nodes), E=512, H=8, Dh=64
// Pipeline: pack(bf16) -> QKV GEMM (MFMA) -> attention (MFMA, full-S) -> out GEMM (MFMA)

#define EMB    512
#define NH     8
#define NGR    64
#define SEQL   256
#define DHEAD  64
#define MROWS  16384   // NGR*SEQL

typedef __attribute__((ext_vector_type(4))) float f32x4;
typedef __attribute__((ext_vector_type(4))) short s16x4;
typedef __attribute__((ext_vector_type(8))) short s16x8;

__device__ __forceinline__ short f2bf(float f) {
  uint32_t u = __builtin_bit_cast(uint32_t, f);
  u += 0x7FFFu + ((u >> 16) & 1u);           // round-to-nearest-even
  return (short)(u >> 16);
}

__device__ __forceinline__ f32x4 mfma16(s16x8 a, s16x8 b, f32x4 c) {
  return __builtin_amdgcn_mfma_f32_16x16x32_bf16(a, b, c, 0, 0, 0);
}

__device__ __forceinline__ void gload_lds16(const void* g, void* l) {
  __builtin_amdgcn_global_load_lds(
      (const __attribute__((address_space(1))) void*)g,
      (__attribute__((address_space(3))) void*)l, 16, 0, 0);
}

// ---------------------------------------------------------------- pack kernels

// value[b*256+l][e] = (l==0) ? metal_x[b][e] : x[b*255+l-1][e], as bf16
__global__ void pack_value(const float* __restrict__ x, const float* __restrict__ mx,
                           short* __restrict__ val) {
  int gid = blockIdx.x * 256 + threadIdx.x;       // 2,097,152 threads, 4 elems each
  int i = gid << 2;
  int row = i >> 9, col = i & 511;
  int b = row >> 8, l = row & 255;
  const float* src = l ? x  + ((size_t)(b * 255 + l - 1) << 9) + col
                       : mx + ((size_t)b << 9) + col;
  f32x4 f = *(const f32x4*)src;
  s16x4 o = { f2bf(f[0]), f2bf(f[1]), f2bf(f[2]), f2bf(f[3]) };
  *(s16x4*)(val + i) = o;
}

// wqkv[(which*512+o)*512+k] bf16 (which: 0=q,1=k,2=v); wo bf16; bias_qkv fp32 concat
__global__ void pack_w(const float* __restrict__ Wq, const float* __restrict__ Wk,
                       const float* __restrict__ Wv, const float* __restrict__ Wo,
                       const float* __restrict__ bq, const float* __restrict__ bk,
                       const float* __restrict__ bv,
                       short* __restrict__ wqkv, short* __restrict__ wo,
                       float* __restrict__ bias_qkv) {
  int gid = blockIdx.x * 256 + threadIdx.x;       // 262,144 threads
  int i = gid << 2;
  const float* src; short* dst;
  if (i < 786432) {
    int which = i >> 18, off = i & 262143;
    src = (which == 0 ? Wq : which == 1 ? Wk : Wv) + off;
    dst = wqkv + i;
  } else {
    int off = i - 786432;
    src = Wo + off; dst = wo + off;
  }
  f32x4 f = *(const f32x4*)src;
  s16x4 o = { f2bf(f[0]), f2bf(f[1]), f2bf(f[2]), f2bf(f[3]) };
  *(s16x4*)dst = o;
  if (gid < 1536)
    bias_qkv[gid] = gid < 512 ? bq[gid] : gid < 1024 ? bk[gid - 512] : bv[gid - 1024];
}

// ------------------------------------------------------------------- GEMM
// C[M=16384, N] = A[M,512](bf16) @ Bt[N,512]^T + bias.
// 128x128 tile, BK=32, 4 waves (2x2), 4x4 16x16x32 frags per wave.
// Minimum-2-phase pipeline (T3 recipe, m230-V0): double-buffered LDS,
// prefetch STAGE(t+1) issued BEFORE compute(t), ONE __syncthreads per iter.
// mode 0: scatter q/k/v [B,H,L,64] bf16.  mode 1: scatter final fp32 output.
#define BM 128
#define BN 128
#define BK 32

__global__ __launch_bounds__(256, 2) void gemm_bt(
    const short* __restrict__ A, const short* __restrict__ Bt,
    const float* __restrict__ bias, int mode,
    short* __restrict__ qb, short* __restrict__ kb, short* __restrict__ vb,
    float* __restrict__ outp) {
  __shared__ short As[2][BM * BK];
  __shared__ short Bs[2][BN * BK];
  const int tid = threadIdx.x;
  const int lane = tid & 63, wid = tid >> 6;
  const int wr = wid >> 1, wc = wid & 1;
  const int l15 = lane & 15, l4 = lane >> 4;
  const int bm = blockIdx.x * BM, bn = blockIdx.y * BN;

  f32x4 acc[4][4];
#pragma unroll
  for (int r = 0; r < 4; ++r)
#pragma unroll
    for (int c = 0; c < 4; ++c) acc[r][c] = (f32x4){0.f, 0.f, 0.f, 0.f};

  // prologue: stage K-tile 0 into buffer 0
#pragma unroll
  for (int i = 0; i < 2; ++i) {
    int idx = i * 256 + tid;
    int row = idx >> 2, cc = (idx & 3) * 8;
    gload_lds16(A + (size_t)(bm + row) * 512 + cc, &As[0][idx * 8]);
    gload_lds16(Bt + (size_t)(bn + row) * 512 + cc, &Bs[0][idx * 8]);
  }
  __syncthreads();                     // drain prologue staging

  int cur = 0;
  for (int t = 0; t < 512 / BK; ++t) {
    // issue next-tile prefetch FIRST (flies under this tile's compute)
    if (t < 512 / BK - 1) {
      const int bk = (t + 1) * BK;
#pragma unroll
      for (int i = 0; i < 2; ++i) {
        int idx = i * 256 + tid;
        int row = idx >> 2, cc = (idx & 3) * 8;
        gload_lds16(A + (size_t)(bm + row) * 512 + bk + cc, &As[cur ^ 1][idx * 8]);
        gload_lds16(Bt + (size_t)(bn + row) * 512 + bk + cc, &Bs[cur ^ 1][idx * 8]);
      }
    }

    s16x8 af[4], bf[4];
#pragma unroll
    for (int r = 0; r < 4; ++r)
      af[r] = *(const s16x8*)(&As[cur][(wr * 64 + r * 16 + l15) * BK + l4 * 8]);
#pragma unroll
    for (int c = 0; c < 4; ++c)
      bf[c] = *(const s16x8*)(&Bs[cur][(wc * 64 + c * 16 + l15) * BK + l4 * 8]);
#pragma unroll
    for (int r = 0; r < 4; ++r)
#pragma unroll
      for (int c = 0; c < 4; ++c)
        acc[r][c] = mfma16(af[r], bf[c], acc[r][c]);

    __syncthreads();                   // vmcnt(0)+lgkmcnt(0)+barrier: prefetch
    cur ^= 1;                          // landed, all reads of buf[cur] retired
  }

  // epilogue: D layout col = lane&15, row = (lane>>4)*4 + reg  [m89-verified]
#pragma unroll
  for (int r = 0; r < 4; ++r) {
    int row0 = bm + wr * 64 + r * 16 + l4 * 4;
#pragma unroll
    for (int c = 0; c < 4; ++c) {
      int col_g = bn + wc * 64 + c * 16 + l15;
      float bvv = bias[col_g];
#pragma unroll
      for (int j = 0; j < 4; ++j) {
        float v = acc[r][c][j] + bvv;
        int row = row0 + j;
        int b = row >> 8, lrow = row & 255;
        if (mode == 0) {
          int which = col_g >> 9, rem = col_g & 511;
          int h = rem >> 6, dh = rem & 63;
          size_t idx = ((size_t)((b * 8 + h) * 256 + lrow)) * 64 + dh;
          (which == 0 ? qb : which == 1 ? kb : vb)[idx] = f2bf(v);
        } else {
          // out_lb is [L,B,E]: l==0 -> metal block, else ((l-1)*64+b)*512+e
          size_t idx = (lrow == 0)
                         ? (size_t)16320 * 512 + (size_t)b * 512 + col_g
                         : ((size_t)(lrow - 1) * 64 + b) * 512 + col_g;
          outp[idx] = v;
        }
      }
    }
  }
}

// ---------------------------------------------------------------- attention
// grid = 2048 blocks: 4 blocks per (bh = b*8+h), each owning 64 query rows
// (4 waves x 16 rows). R10 showed the remaining 52us is latency-bound
// (MfmaUtil 6%, VALU 24%, HBM 10%): QK^T's 32 per-lane global K-loads
// serialize at ~2-4 in flight (68 VGPRs). Fix: stage the 32KB K-tile via
// 8x global_load_lds issued FIRST (DMA flies under VT build), read B-frags
// from LDS with T2 XOR-swizzle. Rule 21: linear LDS dest + inverse-swizzled
// global SOURCE + same XOR on the read (f(o)=((o>>7)&7)<<4, involution,
// row bits preserved; frag-read bank aliasing = 2-way = free per m136).
// NOTE: every loop touching s[] must be FULLY unrolled (rule #20).
#define VT_ROWB 544   // 272 bf16 per row (256 keys + pad), 16B aligned

__global__ __launch_bounds__(256, 2) void attn(
    const short* __restrict__ qb, const short* __restrict__ kb,
    const short* __restrict__ vb, short* __restrict__ attn_out) {
  __shared__ short Kl[256 * 64];        // 32768 B, K tile (xor-swizzled content)
  __shared__ short VT[64 * 272];        // [d][key] swizzled, 34816 B
  __shared__ short Pl[4][16 * 72];      // per-wave P chunk (16 q-rows), 9216 B

  const int tid = threadIdx.x;
  const int lane = tid & 63, w = tid >> 6;
  const int l15 = lane & 15, l4 = lane >> 4;
  const int hb = blockIdx.x;
  const int bh = (hb & 7) * 64 + ((hb >> 3) >> 2);   // XCD-grouped (bijective)
  const int quarter = (hb >> 3) & 3;
  const size_t base = (size_t)bh * SEQL * DHEAD;

  // --- K -> Kl via async DMA, issued first so it hides under VT build.
  // LDS[o] = Kbytes[o ^ ((row(o)&7)<<4)]; read applies the same XOR.
  {
    const char* kbytes = (const char*)(kb + base);
#pragma unroll
    for (int c = 0; c < 8; ++c) {
      int o = c * 4096 + tid * 16;
      int src = o ^ (((o >> 7) & 7) << 4);
      gload_lds16(kbytes + src, (char*)Kl + o);
    }
  }

  // --- V -> VT[d][key] (bf16, XOR-swizzled so both write & b128 read are clean)
  {
    int d0 = (tid & 7) * 8;
    int krow = tid >> 3;                // 0..31
#pragma unroll
    for (int step = 0; step < 8; ++step) {
      int key = step * 32 + krow;
      s16x8 vv = *(const s16x8*)(vb + base + (size_t)key * 64 + d0);
#pragma unroll
      for (int j = 0; j < 8; ++j) {
        int d = d0 + j;
        int off = d * VT_ROWB + ((key * 2) ^ ((d << 1) & 0x70));
        *(short*)((char*)VT + off) = vv[j];
      }
    }
  }

  // --- Q A-frags (one 16-row tile x 2 k-slices)
  const int q0 = quarter * 64 + w * 16;
  s16x8 qf[2];
#pragma unroll
  for (int kk = 0; kk < 2; ++kk)
    qf[kk] = *(const s16x8*)(qb + base + (size_t)(q0 + l15) * 64 + kk * 32 + l4 * 8);

  __syncthreads();                      // drains K-DMA (vmcnt) + VT writes

  // --- S = Q K^T  (per wave: 16 queries x 256 keys), K from swizzled LDS
  f32x4 s[16];
#pragma unroll
  for (int ct = 0; ct < 16; ++ct) s[ct] = (f32x4){0.f, 0.f, 0.f, 0.f};

#pragma unroll                          // FULL unroll: ct must be compile-time
  for (int ct = 0; ct < 16; ++ct) {
    int rawb = (ct * 16 + l15) * 128 + l4 * 16;   // row*128 + dcol bytes
    int swz = (l15 & 7) << 4;                     // = ((row&7)<<4)
    s16x8 kf0 = *(const s16x8*)((const char*)Kl + (rawb ^ swz));
    s16x8 kf1 = *(const s16x8*)((const char*)Kl + ((rawb + 64) ^ swz));
    s[ct] = mfma16(qf[0], kf0, s[ct]);
    s[ct] = mfma16(qf[1], kf1, s[ct]);
  }

  // --- softmax (rows live in (lane>>4)*4+reg; reduce over 16 key-lanes)
  const float scale = 0.125f;           // 1/sqrt(64)
  float lsum[4];
#pragma unroll
  for (int j = 0; j < 4; ++j) {
    float m = -1e30f;
#pragma unroll
    for (int ct = 0; ct < 16; ++ct) m = fmaxf(m, s[ct][j]);
#pragma unroll
    for (int d = 1; d < 16; d <<= 1) m = fmaxf(m, __shfl_xor(m, d, 64));
    m *= scale;
    float ls = 0.f;
#pragma unroll
    for (int ct = 0; ct < 16; ++ct) {
      float p = __expf(s[ct][j] * scale - m);
      s[ct][j] = p;
      ls += p;
    }
#pragma unroll
    for (int d = 1; d < 16; d <<= 1) ls += __shfl_xor(ls, d, 64);
    lsum[j] = ls;
  }

  // --- O = P V  (chunked: stage P 64 keys at a time in per-wave LDS)
  f32x4 o[4];
#pragma unroll
  for (int jt = 0; jt < 4; ++jt) o[jt] = (f32x4){0.f, 0.f, 0.f, 0.f};

#pragma unroll                          // FULL unroll: ck must be compile-time
  for (int ck = 0; ck < 4; ++ck) {
#pragma unroll
    for (int c2 = 0; c2 < 4; ++c2)
#pragma unroll
      for (int j = 0; j < 4; ++j) {
        int q = l4 * 4 + j;             // 0..15
        int col = c2 * 16 + l15;
        Pl[w][q * 72 + col] = f2bf(s[ck * 4 + c2][j]);
      }
    // per-wave LDS: no barrier needed; compiler inserts lgkmcnt waits
#pragma unroll
    for (int kk = 0; kk < 2; ++kk) {
      s16x8 pf = *(const s16x8*)(&Pl[w][l15 * 72 + kk * 32 + l4 * 8]);
#pragma unroll
      for (int jt = 0; jt < 4; ++jt) {
        int d = jt * 16 + l15;
        int k0 = ck * 64 + kk * 32 + l4 * 8;
        int off = d * VT_ROWB + ((k0 * 2) ^ ((d << 1) & 0x70));
        s16x8 vf = *(const s16x8*)((const char*)VT + off);
        o[jt] = mfma16(pf, vf, o[jt]);
      }
    }
  }

  // --- normalize + store as bf16 A-matrix for the out-projection
  const int b = bh >> 3, h = bh & 7;
#pragma unroll
  for (int jt = 0; jt < 4; ++jt)
#pragma unroll
    for (int j = 0; j < 4; ++j) {
      float val = o[jt][j] / lsum[j];
      int qrow = q0 + l4 * 4 + j;
      int d = jt * 16 + l15;
      attn_out[(size_t)(b * 256 + qrow) * 512 + h * 64 + d] = f2bf(val);
    }
}

// ---------------------------------------------------------------- launch

extern "C" void kernel_launch(void* const* d_in, const int* in_sizes, int n_in,
                              void* d_out, int out_size, void* d_ws, size_t ws_size,
                              hipStream_t stream) {
  (void)in_sizes; (void)n_in; (void)out_size; (void)ws_size;
  const float* x  = (const float*)d_in[0];
  const float* mx = (const float*)d_in[1];
  // d_in[2] = batch indices (structure known statically; unused)
  const float* Wq = (const float*)d_in[3];
  const float* Wk = (const float*)d_in[4];
  const float* Wv = (const float*)d_in[5];
  const float* bq = (const float*)d_in[6];
  const float* bk = (const float*)d_in[7];
  const float* bv = (const float*)d_in[8];
  const float* Wo = (const float*)d_in[9];
  const float* bo = (const float*)d_in[10];
  float* out = (float*)d_out;

  char* ws = (char*)d_ws;
  short* value = (short*)(ws);                    // 16,777,216 B
  short* wqkv  = (short*)(ws + 16777216);         //  1,572,864 B
  short* wo    = (short*)(ws + 18350080);         //    524,288 B
  float* biasq = (float*)(ws + 18874368);         //      6,144 B
  short* qbuf  = (short*)(ws + 18880512);         // 16,777,216 B
  short* kbuf  = (short*)(ws + 35657728);         // 16,777,216 B
  short* vbuf  = (short*)(ws + 52434944);         // 16,777,216 B -> 69,212,160 total
  short* attn_o = value;                          // value dead after QKV GEMM

  pack_value<<<8192, 256, 0, stream>>>(x, mx, value);
  pack_w<<<1024, 256, 0, stream>>>(Wq, Wk, Wv, Wo, bq, bk, bv, wqkv, wo, biasq);
  gemm_bt<<<dim3(128, 12), 256, 0, stream>>>(value, wqkv, biasq, 0,
                                             qbuf, kbuf, vbuf, nullptr);
  attn<<<2048, 256, 0, stream>>>(qbuf, kbuf, vbuf, attn_o);
  gemm_bt<<<dim3(128, 4), 256, 0, stream>>>(attn_o, wo, bo, 1,
                                            nullptr, nullptr, nullptr, out);
}

// Round 13
// 184.480 us; speedup vs baseline: 1.1061x; 1.0168x over previous
//
#include <hip/hip_runtime.h>
#include <stdint.h>

// GlobalAddAttention: B=64 graphs, L=256 (1 metal + 255 nodes), E=512, H=8, Dh=64
// Pipeline: pack(bf16) -> QKV GEMM (MFMA) -> attention (MFMA, full-S) -> out GEMM (MFMA)

#define EMB    512
#define NH     8
#define NGR    64
#define SEQL   256
#define DHEAD  64
#define MROWS  16384   // NGR*SEQL

typedef __attribute__((ext_vector_type(4))) float f32x4;
typedef __attribute__((ext_vector_type(4))) short s16x4;
typedef __attribute__((ext_vector_type(8))) short s16x8;

__device__ __forceinline__ short f2bf(float f) {
  uint32_t u = __builtin_bit_cast(uint32_t, f);
  u += 0x7FFFu + ((u >> 16) & 1u);           // round-to-nearest-even
  return (short)(u >> 16);
}

__device__ __forceinline__ f32x4 mfma16(s16x8 a, s16x8 b, f32x4 c) {
  return __builtin_amdgcn_mfma_f32_16x16x32_bf16(a, b, c, 0, 0, 0);
}

__device__ __forceinline__ void gload_lds16(const void* g, void* l) {
  __builtin_amdgcn_global_load_lds(
      (const __attribute__((address_space(1))) void*)g,
      (__attribute__((address_space(3))) void*)l, 16, 0, 0);
}

// ---------------------------------------------------------------- pack kernels

// value[b*256+l][e] = (l==0) ? metal_x[b][e] : x[b*255+l-1][e], as bf16
__global__ void pack_value(const float* __restrict__ x, const float* __restrict__ mx,
                           short* __restrict__ val) {
  int gid = blockIdx.x * 256 + threadIdx.x;       // 2,097,152 threads, 4 elems each
  int i = gid << 2;
  int row = i >> 9, col = i & 511;
  int b = row >> 8, l = row & 255;
  const float* src = l ? x  + ((size_t)(b * 255 + l - 1) << 9) + col
                       : mx + ((size_t)b << 9) + col;
  f32x4 f = *(const f32x4*)src;
  s16x4 o = { f2bf(f[0]), f2bf(f[1]), f2bf(f[2]), f2bf(f[3]) };
  *(s16x4*)(val + i) = o;
}

// wqkv[(which*512+o)*512+k] bf16 (which: 0=q,1=k,2=v); wo bf16; bias_qkv fp32 concat
__global__ void pack_w(const float* __restrict__ Wq, const float* __restrict__ Wk,
                       const float* __restrict__ Wv, const float* __restrict__ Wo,
                       const float* __restrict__ bq, const float* __restrict__ bk,
                       const float* __restrict__ bv,
                       short* __restrict__ wqkv, short* __restrict__ wo,
                       float* __restrict__ bias_qkv) {
  int gid = blockIdx.x * 256 + threadIdx.x;       // 262,144 threads
  int i = gid << 2;
  const float* src; short* dst;
  if (i < 786432) {
    int which = i >> 18, off = i & 262143;
    src = (which == 0 ? Wq : which == 1 ? Wk : Wv) + off;
    dst = wqkv + i;
  } else {
    int off = i - 786432;
    src = Wo + off; dst = wo + off;
  }
  f32x4 f = *(const f32x4*)src;
  s16x4 o = { f2bf(f[0]), f2bf(f[1]), f2bf(f[2]), f2bf(f[3]) };
  *(s16x4*)dst = o;
  if (gid < 1536)
    bias_qkv[gid] = gid < 512 ? bq[gid] : gid < 1024 ? bk[gid - 512] : bv[gid - 1024];
}

// ------------------------------------------------------------------- GEMM
// C[M=16384, N] = A[M,512](bf16) @ Bt[N,512]^T + bias.
// 128x128 tile, BK=32, 4 waves (2x2), 4x4 16x16x32 frags per wave.
// T4 counted-vmcnt pipeline (m218: counted-vs-drain0 = +38%@4k): 3 LDS
// buffers, 2-deep prefetch. Per iter: s_waitcnt vmcnt(4) (tile t landed,
// tile t+1's 4 loads stay IN FLIGHT across the barrier) + raw s_barrier,
// then issue tile t+2, then compute tile t. R11 measured the vmcnt(0)-drain
// 2-phase version flat vs baseline (46.7us, MfmaUtil 21%) — the drain was
// the stall, not the buffering. Last iter peeled with vmcnt(0) (nothing
// newer in flight at t=15, vmcnt(4) would not guarantee tile 15).
// Hazards: buf[(t+2)%3] last read at iter t-1; iter-t barrier (with lgkmcnt
// drain) precedes the issue -> WAR safe. vmcnt(4)+barrier => all waves'
// tile-t data resident before ds_read.
// mode 0: scatter q/k/v [B,H,L,64] bf16.  mode 1: scatter final fp32 output.
#define BM 128
#define BN 128
#define BK 32
#define NT 16          // 512/BK K-tiles

__global__ __launch_bounds__(256, 2) void gemm_bt(
    const short* __restrict__ A, const short* __restrict__ Bt,
    const float* __restrict__ bias, int mode,
    short* __restrict__ qb, short* __restrict__ kb, short* __restrict__ vb,
    float* __restrict__ outp) {
  __shared__ short As[3][BM * BK];
  __shared__ short Bs[3][BN * BK];
  const int tid = threadIdx.x;
  const int lane = tid & 63, wid = tid >> 6;
  const int wr = wid >> 1, wc = wid & 1;
  const int l15 = lane & 15, l4 = lane >> 4;
  const int bm = blockIdx.x * BM, bn = blockIdx.y * BN;

  // 4 gload_lds per thread per tile (2 for A, 2 for B)
  auto STAGE = [&](int t, int b) {
    const int bk = t * BK;
#pragma unroll
    for (int i = 0; i < 2; ++i) {
      int idx = i * 256 + tid;
      int row = idx >> 2, cc = (idx & 3) * 8;
      gload_lds16(A + (size_t)(bm + row) * 512 + bk + cc, &As[b][idx * 8]);
      gload_lds16(Bt + (size_t)(bn + row) * 512 + bk + cc, &Bs[b][idx * 8]);
    }
  };

  f32x4 acc[4][4];
#pragma unroll
  for (int r = 0; r < 4; ++r)
#pragma unroll
    for (int c = 0; c < 4; ++c) acc[r][c] = (f32x4){0.f, 0.f, 0.f, 0.f};

  auto COMPUTE = [&](int b) {
    s16x8 af[4], bf[4];
#pragma unroll
    for (int r = 0; r < 4; ++r)
      af[r] = *(const s16x8*)(&As[b][(wr * 64 + r * 16 + l15) * BK + l4 * 8]);
#pragma unroll
    for (int c = 0; c < 4; ++c)
      bf[c] = *(const s16x8*)(&Bs[b][(wc * 64 + c * 16 + l15) * BK + l4 * 8]);
#pragma unroll
    for (int r = 0; r < 4; ++r)
#pragma unroll
      for (int c = 0; c < 4; ++c)
        acc[r][c] = mfma16(af[r], bf[c], acc[r][c]);
  };

  // prologue: 2 tiles in flight
  STAGE(0, 0);
  STAGE(1, 1);

  int cur = 0;                          // = t % 3
  for (int t = 0; t < NT - 1; ++t) {
    // tile t's 4 loads landed; tile t+1's 4 stay in flight across the barrier
    asm volatile("s_waitcnt vmcnt(4) lgkmcnt(0)" ::: "memory");
    __builtin_amdgcn_s_barrier();
    if (t < NT - 2) {
      int b2 = cur + 2; if (b2 >= 3) b2 -= 3;
      STAGE(t + 2, b2);
    }
    COMPUTE(cur);
    if (++cur == 3) cur = 0;
  }
  // final tile: nothing newer in flight -> full drain
  asm volatile("s_waitcnt vmcnt(0) lgkmcnt(0)" ::: "memory");
  __builtin_amdgcn_s_barrier();
  COMPUTE(cur);

  // epilogue: D layout col = lane&15, row = (lane>>4)*4 + reg  [m89-verified]
#pragma unroll
  for (int r = 0; r < 4; ++r) {
    int row0 = bm + wr * 64 + r * 16 + l4 * 4;
#pragma unroll
    for (int c = 0; c < 4; ++c) {
      int col_g = bn + wc * 64 + c * 16 + l15;
      float bvv = bias[col_g];
#pragma unroll
      for (int j = 0; j < 4; ++j) {
        float v = acc[r][c][j] + bvv;
        int row = row0 + j;
        int b = row >> 8, lrow = row & 255;
        if (mode == 0) {
          int which = col_g >> 9, rem = col_g & 511;
          int h = rem >> 6, dh = rem & 63;
          size_t idx = ((size_t)((b * 8 + h) * 256 + lrow)) * 64 + dh;
          (which == 0 ? qb : which == 1 ? kb : vb)[idx] = f2bf(v);
        } else {
          // out_lb is [L,B,E]: l==0 -> metal block, else ((l-1)*64+b)*512+e
          size_t idx = (lrow == 0)
                         ? (size_t)16320 * 512 + (size_t)b * 512 + col_g
                         : ((size_t)(lrow - 1) * 64 + b) * 512 + col_g;
          outp[idx] = v;
        }
      }
    }
  }
}

// ---------------------------------------------------------------- attention
// grid = 2048 blocks: 4 blocks per (bh = b*8+h), each owning 64 query rows
// (4 waves x 16 rows). K staged via 8x global_load_lds (rule 21: linear LDS
// dest + inverse-swizzled global source + same XOR on read), V transposed
// into XOR-swizzled LDS, P bounced through per-wave LDS.
// NOTE: every loop touching s[] must be FULLY unrolled (rule #20).
#define VT_ROWB 544   // 272 bf16 per row (256 keys + pad), 16B aligned

__global__ __launch_bounds__(256, 2) void attn(
    const short* __restrict__ qb, const short* __restrict__ kb,
    const short* __restrict__ vb, short* __restrict__ attn_out) {
  __shared__ short Kl[256 * 64];        // 32768 B, K tile (xor-swizzled content)
  __shared__ short VT[64 * 272];        // [d][key] swizzled, 34816 B
  __shared__ short Pl[4][16 * 72];      // per-wave P chunk (16 q-rows), 9216 B

  const int tid = threadIdx.x;
  const int lane = tid & 63, w = tid >> 6;
  const int l15 = lane & 15, l4 = lane >> 4;
  const int hb = blockIdx.x;
  const int bh = (hb & 7) * 64 + ((hb >> 3) >> 2);   // XCD-grouped (bijective)
  const int quarter = (hb >> 3) & 3;
  const size_t base = (size_t)bh * SEQL * DHEAD;

  // --- K -> Kl via async DMA, issued first so it hides under VT build.
  // LDS[o] = Kbytes[o ^ ((row(o)&7)<<4)]; read applies the same XOR.
  {
    const char* kbytes = (const char*)(kb + base);
#pragma unroll
    for (int c = 0; c < 8; ++c) {
      int o = c * 4096 + tid * 16;
      int src = o ^ (((o >> 7) & 7) << 4);
      gload_lds16(kbytes + src, (char*)Kl + o);
    }
  }

  // --- V -> VT[d][key] (bf16, XOR-swizzled so both write & b128 read are clean)
  {
    int d0 = (tid & 7) * 8;
    int krow = tid >> 3;                // 0..31
#pragma unroll
    for (int step = 0; step < 8; ++step) {
      int key = step * 32 + krow;
      s16x8 vv = *(const s16x8*)(vb + base + (size_t)key * 64 + d0);
#pragma unroll
      for (int j = 0; j < 8; ++j) {
        int d = d0 + j;
        int off = d * VT_ROWB + ((key * 2) ^ ((d << 1) & 0x70));
        *(short*)((char*)VT + off) = vv[j];
      }
    }
  }

  // --- Q A-frags (one 16-row tile x 2 k-slices)
  const int q0 = quarter * 64 + w * 16;
  s16x8 qf[2];
#pragma unroll
  for (int kk = 0; kk < 2; ++kk)
    qf[kk] = *(const s16x8*)(qb + base + (size_t)(q0 + l15) * 64 + kk * 32 + l4 * 8);

  __syncthreads();                      // drains K-DMA (vmcnt) + VT writes

  // --- S = Q K^T  (per wave: 16 queries x 256 keys), K from swizzled LDS
  f32x4 s[16];
#pragma unroll
  for (int ct = 0; ct < 16; ++ct) s[ct] = (f32x4){0.f, 0.f, 0.f, 0.f};

#pragma unroll                          // FULL unroll: ct must be compile-time
  for (int ct = 0; ct < 16; ++ct) {
    int rawb = (ct * 16 + l15) * 128 + l4 * 16;   // row*128 + dcol bytes
    int swz = (l15 & 7) << 4;                     // = ((row&7)<<4)
    s16x8 kf0 = *(const s16x8*)((const char*)Kl + (rawb ^ swz));
    s16x8 kf1 = *(const s16x8*)((const char*)Kl + ((rawb + 64) ^ swz));
    s[ct] = mfma16(qf[0], kf0, s[ct]);
    s[ct] = mfma16(qf[1], kf1, s[ct]);
  }

  // --- softmax (rows live in (lane>>4)*4+reg; reduce over 16 key-lanes)
  const float scale = 0.125f;           // 1/sqrt(64)
  float lsum[4];
#pragma unroll
  for (int j = 0; j < 4; ++j) {
    float m = -1e30f;
#pragma unroll
    for (int ct = 0; ct < 16; ++ct) m = fmaxf(m, s[ct][j]);
#pragma unroll
    for (int d = 1; d < 16; d <<= 1) m = fmaxf(m, __shfl_xor(m, d, 64));
    m *= scale;
    float ls = 0.f;
#pragma unroll
    for (int ct = 0; ct < 16; ++ct) {
      float p = __expf(s[ct][j] * scale - m);
      s[ct][j] = p;
      ls += p;
    }
#pragma unroll
    for (int d = 1; d < 16; d <<= 1) ls += __shfl_xor(ls, d, 64);
    lsum[j] = ls;
  }

  // --- O = P V  (chunked: stage P 64 keys at a time in per-wave LDS)
  f32x4 o[4];
#pragma unroll
  for (int jt = 0; jt < 4; ++jt) o[jt] = (f32x4){0.f, 0.f, 0.f, 0.f};

#pragma unroll                          // FULL unroll: ck must be compile-time
  for (int ck = 0; ck < 4; ++ck) {
#pragma unroll
    for (int c2 = 0; c2 < 4; ++c2)
#pragma unroll
      for (int j = 0; j < 4; ++j) {
        int q = l4 * 4 + j;             // 0..15
        int col = c2 * 16 + l15;
        Pl[w][q * 72 + col] = f2bf(s[ck * 4 + c2][j]);
      }
    // per-wave LDS: no barrier needed; compiler inserts lgkmcnt waits
#pragma unroll
    for (int kk = 0; kk < 2; ++kk) {
      s16x8 pf = *(const s16x8*)(&Pl[w][l15 * 72 + kk * 32 + l4 * 8]);
#pragma unroll
      for (int jt = 0; jt < 4; ++jt) {
        int d = jt * 16 + l15;
        int k0 = ck * 64 + kk * 32 + l4 * 8;
        int off = d * VT_ROWB + ((k0 * 2) ^ ((d << 1) & 0x70));
        s16x8 vf = *(const s16x8*)((const char*)VT + off);
        o[jt] = mfma16(pf, vf, o[jt]);
      }
    }
  }

  // --- normalize + store as bf16 A-matrix for the out-projection
  const int b = bh >> 3, h = bh & 7;
#pragma unroll
  for (int jt = 0; jt < 4; ++jt)
#pragma unroll
    for (int j = 0; j < 4; ++j) {
      float val = o[jt][j] / lsum[j];
      int qrow = q0 + l4 * 4 + j;
      int d = jt * 16 + l15;
      attn_out[(size_t)(b * 256 + qrow) * 512 + h * 64 + d] = f2bf(val);
    }
}

// ---------------------------------------------------------------- launch

extern "C" void kernel_launch(void* const* d_in, const int* in_sizes, int n_in,
                              void* d_out, int out_size, void* d_ws, size_t ws_size,
                              hipStream_t stream) {
  (void)in_sizes; (void)n_in; (void)out_size; (void)ws_size;
  const float* x  = (const float*)d_in[0];
  const float* mx = (const float*)d_in[1];
  // d_in[2] = batch indices (structure known statically; unused)
  const float* Wq = (const float*)d_in[3];
  const float* Wk = (const float*)d_in[4];
  const float* Wv = (const float*)d_in[5];
  const float* bq = (const float*)d_in[6];
  const float* bk = (const float*)d_in[7];
  const float* bv = (const float*)d_in[8];
  const float* Wo = (const float*)d_in[9];
  const float* bo = (const float*)d_in[10];
  float* out = (float*)d_out;

  char* ws = (char*)d_ws;
  short* value = (short*)(ws);                    // 16,777,216 B
  short* wqkv  = (short*)(ws + 16777216);         //  1,572,864 B
  short* wo    = (short*)(ws + 18350080);         //    524,288 B
  float* biasq = (float*)(ws + 18874368);         //      6,144 B
  short* qbuf  = (short*)(ws + 18880512);         // 16,777,216 B
  short* kbuf  = (short*)(ws + 35657728);         // 16,777,216 B
  short* vbuf  = (short*)(ws + 52434944);         // 16,777,216 B -> 69,212,160 total
  short* attn_o = value;                          // value dead after QKV GEMM

  pack_value<<<8192, 256, 0, stream>>>(x, mx, value);
  pack_w<<<1024, 256, 0, stream>>>(Wq, Wk, Wv, Wo, bq, bk, bv, wqkv, wo, biasq);
  gemm_bt<<<dim3(128, 12), 256, 0, stream>>>(value, wqkv, biasq, 0,
                                             qbuf, kbuf, vbuf, nullptr);
  attn<<<2048, 256, 0, stream>>>(qbuf, kbuf, vbuf, attn_o);
  gemm_bt<<<dim3(128, 4), 256, 0, stream>>>(attn_o, wo, bo, 1,
                                            nullptr, nullptr, nullptr, out);
}